// Round 1
// baseline (1346.304 us; speedup 1.0000x reference)
//
#include <hip/hip_runtime.h>
#include <hip/hip_bf16.h>
#include <cstdint>
#include <cstddef>

#define BATCH 2
#define S_LEN 2048
#define D_DIM 2048
#define NH 16
#define DHEAD 128

typedef __bf16 bf16;
typedef __attribute__((ext_vector_type(8))) __bf16 bf16x8;
typedef __attribute__((ext_vector_type(4))) __bf16 bf16x4;
typedef __attribute__((ext_vector_type(4))) float f32x4;

// async global->LDS, 16B per lane. HW writes lane data at (uniform lds base + lane*16).
__device__ __forceinline__ void async16(const void* g, void* l) {
  __builtin_amdgcn_global_load_lds((__attribute__((address_space(1))) void*)g,
                                   (__attribute__((address_space(3))) void*)l,
                                   16, 0, 0);
}

// ---------------- cast fp32 -> bf16 ----------------
__global__ __launch_bounds__(256) void cast_kernel(const float4* __restrict__ in,
                                                   bf16x4* __restrict__ out, int n4) {
  int i = blockIdx.x * 256 + threadIdx.x;
  if (i < n4) {
    float4 v = in[i];
    bf16x4 o;
    o[0] = (bf16)v.x; o[1] = (bf16)v.y; o[2] = (bf16)v.z; o[3] = (bf16)v.w;
    out[i] = o;
  }
}

// ---------------- GEMM: C[M,N] = A[M,K] * Bm[N,K]^T (both row-major, bf16) ----------------
// 128x128 block tile, BK=32, 256 threads = 4 waves (2x2), 64x64 per wave.
// LDS chunk layout: chunk c = k8*128 + row  (16B chunks) -> frag ds_read_b128 conflict-free.
__global__ __launch_bounds__(256) void gemm_bt(const bf16* __restrict__ A,
                                               const bf16* __restrict__ Bm,
                                               float* __restrict__ Cf,
                                               bf16* __restrict__ Cb,
                                               int M, int N, int K) {
  __shared__ __align__(16) bf16 As[128 * 32];
  __shared__ __align__(16) bf16 Bs[128 * 32];
  const int tid = threadIdx.x;
  const int wave = tid >> 6, lane = tid & 63;
  const int quad = lane >> 4, l16 = lane & 15;
  const int wm = (wave >> 1) * 64, wn = (wave & 1) * 64;
  const int m0 = blockIdx.y * 128, n0 = blockIdx.x * 128;

  f32x4 acc[4][4];
#pragma unroll
  for (int i = 0; i < 4; ++i)
#pragma unroll
    for (int j = 0; j < 4; ++j) acc[i][j] = (f32x4){0.f, 0.f, 0.f, 0.f};

  for (int k0 = 0; k0 < K; k0 += 32) {
    __syncthreads();
#pragma unroll
    for (int i = 0; i < 2; ++i) {
      int c = i * 256 + tid;
      int row = c & 127, k8 = c >> 7;
      async16(A + (size_t)(m0 + row) * K + k0 + k8 * 8, (void*)(As + (i * 256 + wave * 64) * 8));
      async16(Bm + (size_t)(n0 + row) * K + k0 + k8 * 8, (void*)(Bs + (i * 256 + wave * 64) * 8));
    }
    __builtin_amdgcn_s_waitcnt(0);
    __syncthreads();
    bf16x8 af[4], bfr[4];
#pragma unroll
    for (int i = 0; i < 4; ++i)
      af[i] = *(const bf16x8*)(As + (quad * 128 + wm + i * 16 + l16) * 8);
#pragma unroll
    for (int j = 0; j < 4; ++j)
      bfr[j] = *(const bf16x8*)(Bs + (quad * 128 + wn + j * 16 + l16) * 8);
#pragma unroll
    for (int i = 0; i < 4; ++i)
#pragma unroll
      for (int j = 0; j < 4; ++j)
        acc[i][j] = __builtin_amdgcn_mfma_f32_16x16x32_bf16(af[i], bfr[j], acc[i][j], 0, 0, 0);
  }
  // epilogue: C/D layout col=lane&15, row=quad*4+r
#pragma unroll
  for (int i = 0; i < 4; ++i)
#pragma unroll
    for (int j = 0; j < 4; ++j)
#pragma unroll
      for (int r = 0; r < 4; ++r) {
        int row = m0 + wm + i * 16 + quad * 4 + r;
        int col = n0 + wn + j * 16 + l16;
        if (Cf) Cf[(size_t)row * N + col] = acc[i][j][r];
        else    Cb[(size_t)row * N + col] = (bf16)acc[i][j][r];
      }
}

// ---------------- transpose V[b*s][D] (per head slice) -> Vt[b,h,d,s] ----------------
__global__ __launch_bounds__(256) void transpose_v(const bf16* __restrict__ V,
                                                   bf16* __restrict__ Vt) {
  __shared__ __align__(16) bf16 tileT[64 * 80];  // [d_local][s_local], pad 80
  const int tid = threadIdx.x;
  const int bh = blockIdx.z, b = bh >> 4, h = bh & 15;
  const int s0 = blockIdx.x * 64, d0 = blockIdx.y * 64;
  const int i = tid >> 3;          // 0..31
  const int jc = (tid & 7) * 8;    // 0..56 step 8
#pragma unroll
  for (int ii = 0; ii < 2; ++ii) {
    int si = i + ii * 32;
    bf16x8 v = *(const bf16x8*)(V + (size_t)(b * S_LEN + s0 + si) * D_DIM + h * DHEAD + d0 + jc);
#pragma unroll
    for (int u = 0; u < 8; ++u) tileT[(jc + u) * 80 + si] = v[u];
  }
  __syncthreads();
#pragma unroll
  for (int jj = 0; jj < 2; ++jj) {
    int jr = i + jj * 32;  // d row 0..63
    bf16x8 o = *(const bf16x8*)(tileT + jr * 80 + jc);
    *(bf16x8*)(Vt + ((size_t)bh * DHEAD + d0 + jr) * S_LEN + s0 + jc) = o;
  }
}

// ---------------- fused causal attention ----------------
// grid: x = 32 m-strips (reversed: longest first), y = 32 (b*h). block 256 = 4 waves.
// Each wave owns 16 q-rows of the 64-row strip.
__global__ __launch_bounds__(256) void attn_kernel(const bf16* __restrict__ Q,
                                                   const bf16* __restrict__ Kg,
                                                   const bf16* __restrict__ Vt,
                                                   float* __restrict__ P,
                                                   bf16* __restrict__ AO) {
  __shared__ __align__(16) bf16 Qs[64 * 128];        // chunk c = k8*64 + row
  __shared__ __align__(16) bf16 KVs[128 * 128];      // chunk c = k8*128 + row
  __shared__ __align__(16) bf16 Ps[4][16 * 128];     // per-wave P slice, chunk c = k8*16 + m
  const int tid = threadIdx.x, wave = tid >> 6, lane = tid & 63;
  const int quad = lane >> 4, l16 = lane & 15;
  const int bh = blockIdx.y, b = bh >> 4, h = bh & 15;
  const int mt = (int)gridDim.x - 1 - (int)blockIdx.x;  // longest strips dispatched first
  const int m0 = mt * 64;
  const int ntc = mt / 2 + 1;  // causal tiles of 128 cols
  const bf16* Qh = Q + (size_t)b * S_LEN * D_DIM + h * DHEAD;
  const bf16* Kh = Kg + (size_t)b * S_LEN * D_DIM + h * DHEAD;
  const bf16* Vth = Vt + (size_t)bh * DHEAD * S_LEN;
  float* Pb = P + ((size_t)bh * S_LEN + m0) * S_LEN;
  const float scale = 0.08838834764831845f;  // 1/sqrt(128)

  // stage Q strip (64x128)
#pragma unroll
  for (int i = 0; i < 4; ++i) {
    int c = i * 256 + tid;
    int row = c & 63, k8 = c >> 6;
    async16(Qh + (size_t)(m0 + row) * D_DIM + k8 * 8, (void*)(Qs + (i * 256 + wave * 64) * 8));
  }
  __builtin_amdgcn_s_waitcnt(0);
  __syncthreads();
  bf16x8 aq[4];
#pragma unroll
  for (int kt = 0; kt < 4; ++kt)
    aq[kt] = *(const bf16x8*)(Qs + ((kt * 4 + quad) * 64 + wave * 16 + l16) * 8);

  float mrun[4], lrun[4];
#pragma unroll
  for (int r = 0; r < 4; ++r) { mrun[r] = -1e30f; lrun[r] = 0.f; }
  const int row_base = m0 + wave * 16 + quad * 4;

  // ---- pass 1: online softmax stats (m, l) ----
  for (int t = 0; t < ntc; ++t) {
    const int n0 = t * 128;
    __syncthreads();
#pragma unroll
    for (int i = 0; i < 8; ++i) {
      int c = i * 256 + tid;
      int row = c & 127, k8 = c >> 7;
      async16(Kh + (size_t)(n0 + row) * D_DIM + k8 * 8, (void*)(KVs + (i * 256 + wave * 64) * 8));
    }
    __builtin_amdgcn_s_waitcnt(0);
    __syncthreads();
    f32x4 sacc[8];
#pragma unroll
    for (int jt = 0; jt < 8; ++jt) sacc[jt] = (f32x4){0.f, 0.f, 0.f, 0.f};
#pragma unroll
    for (int jt = 0; jt < 8; ++jt)
#pragma unroll
      for (int kt = 0; kt < 4; ++kt) {
        bf16x8 bk = *(const bf16x8*)(KVs + ((kt * 4 + quad) * 128 + jt * 16 + l16) * 8);
        sacc[jt] = __builtin_amdgcn_mfma_f32_16x16x32_bf16(aq[kt], bk, sacc[jt], 0, 0, 0);
      }
#pragma unroll
    for (int r = 0; r < 4; ++r) {
      int rowg = row_base + r;
      float tmax = -1e30f;
#pragma unroll
      for (int jt = 0; jt < 8; ++jt) {
        int colg = n0 + jt * 16 + l16;
        float s = (colg <= rowg) ? sacc[jt][r] * scale : -1e30f;
        sacc[jt][r] = s;
        tmax = fmaxf(tmax, s);
      }
      tmax = fmaxf(tmax, __shfl_xor(tmax, 1));
      tmax = fmaxf(tmax, __shfl_xor(tmax, 2));
      tmax = fmaxf(tmax, __shfl_xor(tmax, 4));
      tmax = fmaxf(tmax, __shfl_xor(tmax, 8));
      float mnew = fmaxf(mrun[r], tmax);
      float ps = 0.f;
#pragma unroll
      for (int jt = 0; jt < 8; ++jt) ps += __expf(sacc[jt][r] - mnew);
      ps += __shfl_xor(ps, 1);
      ps += __shfl_xor(ps, 2);
      ps += __shfl_xor(ps, 4);
      ps += __shfl_xor(ps, 8);
      lrun[r] = lrun[r] * __expf(mrun[r] - mnew) + ps;
      mrun[r] = mnew;
    }
  }
  float linv[4];
#pragma unroll
  for (int r = 0; r < 4; ++r) linv[r] = 1.0f / lrun[r];

  // ---- pass 2: recompute S, write P (fp32 -> d_out, bf16 -> LDS), PV accumulate ----
  f32x4 oacc[8];
#pragma unroll
  for (int jt = 0; jt < 8; ++jt) oacc[jt] = (f32x4){0.f, 0.f, 0.f, 0.f};
  bf16* myPs = Ps[wave];

  for (int t = 0; t < 16; ++t) {
    const int n0 = t * 128;
    if (t < ntc) {
      __syncthreads();
#pragma unroll
      for (int i = 0; i < 8; ++i) {
        int c = i * 256 + tid;
        int row = c & 127, k8 = c >> 7;
        async16(Kh + (size_t)(n0 + row) * D_DIM + k8 * 8, (void*)(KVs + (i * 256 + wave * 64) * 8));
      }
      __builtin_amdgcn_s_waitcnt(0);
      __syncthreads();
      f32x4 sacc[8];
#pragma unroll
      for (int jt = 0; jt < 8; ++jt) sacc[jt] = (f32x4){0.f, 0.f, 0.f, 0.f};
#pragma unroll
      for (int jt = 0; jt < 8; ++jt)
#pragma unroll
        for (int kt = 0; kt < 4; ++kt) {
          bf16x8 bk = *(const bf16x8*)(KVs + ((kt * 4 + quad) * 128 + jt * 16 + l16) * 8);
          sacc[jt] = __builtin_amdgcn_mfma_f32_16x16x32_bf16(aq[kt], bk, sacc[jt], 0, 0, 0);
        }
#pragma unroll
      for (int jt = 0; jt < 8; ++jt)
#pragma unroll
        for (int r = 0; r < 4; ++r) {
          int rowg = row_base + r;
          int colg = n0 + jt * 16 + l16;
          float p = (colg <= rowg) ? __expf(sacc[jt][r] * scale - mrun[r]) * linv[r] : 0.f;
          Pb[(size_t)(wave * 16 + quad * 4 + r) * S_LEN + colg] = p;
          int kk = jt * 16 + l16;
          int m = quad * 4 + r;
          myPs[((kk >> 3) * 16 + m) * 8 + (kk & 7)] = (bf16)p;
        }
      __syncthreads();  // all waves done reading K tile; reuse KVs for Vt
#pragma unroll
      for (int i = 0; i < 8; ++i) {
        int c = i * 256 + tid;
        int row = c & 127, k8 = c >> 7;  // row = d, k8 = kv chunk
        async16(Vth + (size_t)row * S_LEN + n0 + k8 * 8, (void*)(KVs + (i * 256 + wave * 64) * 8));
      }
      __builtin_amdgcn_s_waitcnt(0);
      __syncthreads();
      bf16x8 ap[4];
#pragma unroll
      for (int kt = 0; kt < 4; ++kt)
        ap[kt] = *(const bf16x8*)(myPs + ((kt * 4 + quad) * 16 + l16) * 8);
#pragma unroll
      for (int jt = 0; jt < 8; ++jt)
#pragma unroll
        for (int kt = 0; kt < 4; ++kt) {
          bf16x8 bv = *(const bf16x8*)(KVs + ((kt * 4 + quad) * 128 + jt * 16 + l16) * 8);
          oacc[jt] = __builtin_amdgcn_mfma_f32_16x16x32_bf16(ap[kt], bv, oacc[jt], 0, 0, 0);
        }
    } else {
      // fully-masked tile: write zeros (d_out is poisoned every launch)
      float4 z = make_float4(0.f, 0.f, 0.f, 0.f);
#pragma unroll
      for (int i = 0; i < 8; ++i) {
        int idx = i * 256 + tid;
        int row = idx >> 5, c4 = idx & 31;
        *(float4*)(Pb + (size_t)row * S_LEN + n0 + c4 * 4) = z;
      }
    }
  }
  // epilogue: attn_out bf16, layout [b*s][D] with head offset
  bf16* AOb = AO + ((size_t)(b * S_LEN + m0 + wave * 16 + quad * 4)) * D_DIM + h * DHEAD;
#pragma unroll
  for (int jt = 0; jt < 8; ++jt)
#pragma unroll
    for (int r = 0; r < 4; ++r)
      AOb[(size_t)r * D_DIM + jt * 16 + l16] = (bf16)oacc[jt][r];
}

// ---------------- launcher ----------------
extern "C" void kernel_launch(void* const* d_in, const int* in_sizes, int n_in,
                              void* d_out, int out_size, void* d_ws, size_t ws_size,
                              hipStream_t stream) {
  const float* x  = (const float*)d_in[0];
  // d_in[1] = mask (known causal tril; structure used directly)
  const float* wq = (const float*)d_in[2];
  const float* wk = (const float*)d_in[3];
  const float* wv = (const float*)d_in[4];
  const float* wo = (const float*)d_in[5];
  float* out = (float*)d_out;

  const size_t NX = (size_t)BATCH * S_LEN * D_DIM;  // 8388608
  const size_t NW = (size_t)D_DIM * D_DIM;          // 4194304
  bf16* ws = (bf16*)d_ws;
  bf16* Xb = ws;
  bf16* Wq = Xb + NX;
  bf16* Wk = Wq + NW;
  bf16* Wv = Wk + NW;
  bf16* Wo = Wv + NW;
  bf16* Qm = Wo + NW;
  bf16* Km = Qm + NX;
  bf16* Vm = Km + NX;
  bf16* Vt = Vm + NX;
  bf16* AOm = Vt + NX;

  // casts
  cast_kernel<<<(int)(NX / 4 / 256), 256, 0, stream>>>((const float4*)x, (bf16x4*)Xb, (int)(NX / 4));
  cast_kernel<<<(int)(NW / 4 / 256), 256, 0, stream>>>((const float4*)wq, (bf16x4*)Wq, (int)(NW / 4));
  cast_kernel<<<(int)(NW / 4 / 256), 256, 0, stream>>>((const float4*)wk, (bf16x4*)Wk, (int)(NW / 4));
  cast_kernel<<<(int)(NW / 4 / 256), 256, 0, stream>>>((const float4*)wv, (bf16x4*)Wv, (int)(NW / 4));
  cast_kernel<<<(int)(NW / 4 / 256), 256, 0, stream>>>((const float4*)wo, (bf16x4*)Wo, (int)(NW / 4));

  // projections: Q/K/V = Xb @ W^T  (M=4096, N=2048, K=2048)
  dim3 gg(D_DIM / 128, (unsigned)(BATCH * S_LEN / 128));
  gemm_bt<<<gg, 256, 0, stream>>>(Xb, Wq, nullptr, Qm, BATCH * S_LEN, D_DIM, D_DIM);
  gemm_bt<<<gg, 256, 0, stream>>>(Xb, Wk, nullptr, Km, BATCH * S_LEN, D_DIM, D_DIM);
  gemm_bt<<<gg, 256, 0, stream>>>(Xb, Wv, nullptr, Vm, BATCH * S_LEN, D_DIM, D_DIM);

  // V -> Vt[b,h,d,s]
  transpose_v<<<dim3(S_LEN / 64, DHEAD / 64, BATCH * NH), 256, 0, stream>>>(Vm, Vt);

  // fused attention; P written to d_out after output region
  attn_kernel<<<dim3(S_LEN / 64, BATCH * NH), 256, 0, stream>>>(Qm, Km, Vt, out + NX, AOm);

  // output = AO @ Wo^T (fp32 out)
  gemm_bt<<<gg, 256, 0, stream>>>(AOm, Wo, out, nullptr, BATCH * S_LEN, D_DIM, D_DIM);
}

// Round 2
// 1232.995 us; speedup vs baseline: 1.0919x; 1.0919x over previous
//
#include <hip/hip_runtime.h>
#include <hip/hip_bf16.h>
#include <cstdint>
#include <cstddef>

#define BATCH 2
#define S_LEN 2048
#define D_DIM 2048
#define NH 16
#define DHEAD 128
#define NXE ((size_t)BATCH * S_LEN * D_DIM)  // 8388608
#define NWE ((size_t)D_DIM * D_DIM)          // 4194304

typedef __bf16 bf16;
typedef __attribute__((ext_vector_type(8))) __bf16 bf16x8;
typedef __attribute__((ext_vector_type(4))) __bf16 bf16x4;
typedef __attribute__((ext_vector_type(4))) float f32x4;

__device__ __forceinline__ void async16(const void* g, void* l) {
  __builtin_amdgcn_global_load_lds((__attribute__((address_space(1))) void*)g,
                                   (__attribute__((address_space(3))) void*)l,
                                   16, 0, 0);
}

// ---------------- cast fp32 -> bf16 ----------------
__global__ __launch_bounds__(256) void cast_kernel(const float4* __restrict__ in,
                                                   bf16x4* __restrict__ out, int n4) {
  int i = blockIdx.x * 256 + threadIdx.x;
  if (i < n4) {
    float4 v = in[i];
    bf16x4 o;
    o[0] = (bf16)v.x; o[1] = (bf16)v.y; o[2] = (bf16)v.z; o[3] = (bf16)v.w;
    out[i] = o;
  }
}

// ---------------- fused QKV GEMM: C_mat[row, n%2048] = A @ Wf^T, Wf = [Wq;Wk;Wv] ----------------
// 128x128 tile, BK=32, 4 waves (2x2), 64x64/wave. LDS chunk c = k8*rows + row.
__global__ __launch_bounds__(256) void gemm_qkv(const bf16* __restrict__ A,
                                                const bf16* __restrict__ Wf,
                                                bf16* __restrict__ C0) {
  __shared__ __align__(16) bf16 As[128 * 32];
  __shared__ __align__(16) bf16 Bs[128 * 32];
  const int tid = threadIdx.x;
  const int wave = tid >> 6, lane = tid & 63;
  const int quad = lane >> 4, l16 = lane & 15;
  const int wm = (wave >> 1) * 64, wn = (wave & 1) * 64;
  const int m0 = blockIdx.y * 128, n0 = blockIdx.x * 128;
  const int K = D_DIM;

  f32x4 acc[4][4];
#pragma unroll
  for (int i = 0; i < 4; ++i)
#pragma unroll
    for (int j = 0; j < 4; ++j) acc[i][j] = (f32x4){0.f, 0.f, 0.f, 0.f};

  for (int k0 = 0; k0 < K; k0 += 32) {
    __syncthreads();
#pragma unroll
    for (int i = 0; i < 2; ++i) {
      int c = i * 256 + tid;
      int row = c & 127, k8 = c >> 7;
      async16(A + (size_t)(m0 + row) * K + k0 + k8 * 8, (void*)(As + (i * 256 + wave * 64) * 8));
      async16(Wf + (size_t)(n0 + row) * K + k0 + k8 * 8, (void*)(Bs + (i * 256 + wave * 64) * 8));
    }
    __builtin_amdgcn_s_waitcnt(0);
    __syncthreads();
    bf16x8 af[4], bfr[4];
#pragma unroll
    for (int i = 0; i < 4; ++i)
      af[i] = *(const bf16x8*)(As + (quad * 128 + wm + i * 16 + l16) * 8);
#pragma unroll
    for (int j = 0; j < 4; ++j)
      bfr[j] = *(const bf16x8*)(Bs + (quad * 128 + wn + j * 16 + l16) * 8);
#pragma unroll
    for (int i = 0; i < 4; ++i)
#pragma unroll
      for (int j = 0; j < 4; ++j)
        acc[i][j] = __builtin_amdgcn_mfma_f32_16x16x32_bf16(af[i], bfr[j], acc[i][j], 0, 0, 0);
  }
  const int mat = n0 >> 11;
  const int cb = n0 & 2047;
  bf16* Cm = C0 + (size_t)mat * NXE;
#pragma unroll
  for (int i = 0; i < 4; ++i)
#pragma unroll
    for (int j = 0; j < 4; ++j)
#pragma unroll
      for (int r = 0; r < 4; ++r) {
        int row = m0 + wm + i * 16 + quad * 4 + r;
        int col = cb + wn + j * 16 + l16;
        Cm[(size_t)row * D_DIM + col] = (bf16)acc[i][j][r];
      }
}

// ---------------- out-proj GEMM: fp32 C = A @ B^T, M=4096 N=2048 K=2048 ----------------
__global__ __launch_bounds__(256) void gemm_out(const bf16* __restrict__ A,
                                                const bf16* __restrict__ Bm,
                                                float* __restrict__ Cf) {
  __shared__ __align__(16) bf16 As[128 * 32];
  __shared__ __align__(16) bf16 Bs[128 * 32];
  const int tid = threadIdx.x;
  const int wave = tid >> 6, lane = tid & 63;
  const int quad = lane >> 4, l16 = lane & 15;
  const int wm = (wave >> 1) * 64, wn = (wave & 1) * 64;
  const int m0 = blockIdx.y * 128, n0 = blockIdx.x * 128;
  const int K = D_DIM, N = D_DIM;

  f32x4 acc[4][4];
#pragma unroll
  for (int i = 0; i < 4; ++i)
#pragma unroll
    for (int j = 0; j < 4; ++j) acc[i][j] = (f32x4){0.f, 0.f, 0.f, 0.f};

  for (int k0 = 0; k0 < K; k0 += 32) {
    __syncthreads();
#pragma unroll
    for (int i = 0; i < 2; ++i) {
      int c = i * 256 + tid;
      int row = c & 127, k8 = c >> 7;
      async16(A + (size_t)(m0 + row) * K + k0 + k8 * 8, (void*)(As + (i * 256 + wave * 64) * 8));
      async16(Bm + (size_t)(n0 + row) * K + k0 + k8 * 8, (void*)(Bs + (i * 256 + wave * 64) * 8));
    }
    __builtin_amdgcn_s_waitcnt(0);
    __syncthreads();
    bf16x8 af[4], bfr[4];
#pragma unroll
    for (int i = 0; i < 4; ++i)
      af[i] = *(const bf16x8*)(As + (quad * 128 + wm + i * 16 + l16) * 8);
#pragma unroll
    for (int j = 0; j < 4; ++j)
      bfr[j] = *(const bf16x8*)(Bs + (quad * 128 + wn + j * 16 + l16) * 8);
#pragma unroll
    for (int i = 0; i < 4; ++i)
#pragma unroll
      for (int j = 0; j < 4; ++j)
        acc[i][j] = __builtin_amdgcn_mfma_f32_16x16x32_bf16(af[i], bfr[j], acc[i][j], 0, 0, 0);
  }
#pragma unroll
  for (int i = 0; i < 4; ++i)
#pragma unroll
    for (int j = 0; j < 4; ++j)
#pragma unroll
      for (int r = 0; r < 4; ++r) {
        int row = m0 + wm + i * 16 + quad * 4 + r;
        int col = n0 + wn + j * 16 + l16;
        Cf[(size_t)row * N + col] = acc[i][j][r];
      }
}

// ---------------- transpose V[b*s][D] (per head slice) -> Vt[b,h,d,s] ----------------
__global__ __launch_bounds__(256) void transpose_v(const bf16* __restrict__ V,
                                                   bf16* __restrict__ Vt) {
  __shared__ __align__(16) bf16 tileT[64 * 80];
  const int tid = threadIdx.x;
  const int bh = blockIdx.z, b = bh >> 4, h = bh & 15;
  const int s0 = blockIdx.x * 64, d0 = blockIdx.y * 64;
  const int i = tid >> 3;
  const int jc = (tid & 7) * 8;
#pragma unroll
  for (int ii = 0; ii < 2; ++ii) {
    int si = i + ii * 32;
    bf16x8 v = *(const bf16x8*)(V + (size_t)(b * S_LEN + s0 + si) * D_DIM + h * DHEAD + d0 + jc);
#pragma unroll
    for (int u = 0; u < 8; ++u) tileT[(jc + u) * 80 + si] = v[u];
  }
  __syncthreads();
#pragma unroll
  for (int jj = 0; jj < 2; ++jj) {
    int jr = i + jj * 32;
    bf16x8 o = *(const bf16x8*)(tileT + jr * 80 + jc);
    *(bf16x8*)(Vt + ((size_t)bh * DHEAD + d0 + jr) * S_LEN + s0 + jc) = o;
  }
}

// ---------------- fused causal attention ----------------
// grid: x = 32 m-strips (longest first), y = 32 (b*h). 4 waves, 16 q-rows each.
// LDS 48 KB -> 3 blocks/CU. Pass1: lane-local online (m,l), one cross-lane merge at end.
__global__ __launch_bounds__(256, 3) void attn_kernel(const bf16* __restrict__ Q,
                                                      const bf16* __restrict__ Kg,
                                                      const bf16* __restrict__ Vt,
                                                      float* __restrict__ P,
                                                      bf16* __restrict__ AO) {
  __shared__ __align__(16) bf16 KVs[128 * 128];   // chunk c = k8*128 + row
  __shared__ __align__(16) bf16 Ps[4][16 * 128];  // per-wave, chunk c = (col>>3)*16 + row
  const int tid = threadIdx.x, wave = tid >> 6, lane = tid & 63;
  const int quad = lane >> 4, l16 = lane & 15;
  const int bh = blockIdx.y, b = bh >> 4, h = bh & 15;
  const int mt = (int)gridDim.x - 1 - (int)blockIdx.x;
  const int m0 = mt * 64;
  const int ntc = mt / 2 + 1;
  const bf16* Qh = Q + (size_t)b * S_LEN * D_DIM + h * DHEAD;
  const bf16* Kh = Kg + (size_t)b * S_LEN * D_DIM + h * DHEAD;
  const bf16* Vth = Vt + (size_t)bh * DHEAD * S_LEN;
  float* Pb = P + ((size_t)bh * S_LEN + m0) * S_LEN;
  const float scale = 0.08838834764831845f;  // 1/sqrt(128)

  // Q fragment: direct global -> registers (A-layout: m=l16, k=kt*32+quad*8+j)
  bf16x8 aq[4];
  const bf16* qrow = Qh + (size_t)(m0 + wave * 16 + l16) * D_DIM + quad * 8;
#pragma unroll
  for (int kt = 0; kt < 4; ++kt) aq[kt] = *(const bf16x8*)(qrow + kt * 32);

  const int row_base = m0 + wave * 16 + quad * 4;
  float mrun[4], lrun[4];
#pragma unroll
  for (int r = 0; r < 4; ++r) { mrun[r] = -1e30f; lrun[r] = 0.f; }

  // ---- pass 1: lane-local online stats ----
  for (int t = 0; t < ntc; ++t) {
    const int n0 = t * 128;
    __syncthreads();
#pragma unroll
    for (int i = 0; i < 8; ++i) {
      int c = i * 256 + tid;
      int row = c & 127, k8 = c >> 7;
      async16(Kh + (size_t)(n0 + row) * D_DIM + k8 * 8, (void*)(KVs + (i * 256 + wave * 64) * 8));
    }
    __builtin_amdgcn_s_waitcnt(0);
    __syncthreads();
    f32x4 sacc[8];
#pragma unroll
    for (int jt = 0; jt < 8; ++jt) sacc[jt] = (f32x4){0.f, 0.f, 0.f, 0.f};
#pragma unroll
    for (int jt = 0; jt < 8; ++jt)
#pragma unroll
      for (int kt = 0; kt < 4; ++kt) {
        bf16x8 bk = *(const bf16x8*)(KVs + ((kt * 4 + quad) * 128 + jt * 16 + l16) * 8);
        sacc[jt] = __builtin_amdgcn_mfma_f32_16x16x32_bf16(aq[kt], bk, sacc[jt], 0, 0, 0);
      }
    const bool full = (n0 + 127 <= m0);  // wave-uniform
#pragma unroll
    for (int r = 0; r < 4; ++r) {
      const int rowg = row_base + r;
      float s[8], tmax = -3.0e38f;
#pragma unroll
      for (int jt = 0; jt < 8; ++jt) {
        float v = sacc[jt][r] * scale;
        if (!full) { int colg = n0 + jt * 16 + l16; v = (colg <= rowg) ? v : -3.0e38f; }
        s[jt] = v;
        tmax = fmaxf(tmax, v);
      }
      float mnew = fmaxf(mrun[r], tmax);
      float ps = 0.f;
#pragma unroll
      for (int jt = 0; jt < 8; ++jt) ps += __expf(s[jt] - mnew);
      lrun[r] = lrun[r] * __expf(mrun[r] - mnew) + ps;
      mrun[r] = mnew;
    }
  }
  // one cross-lane merge (16 lanes share the same 4 rows)
  float linv[4];
#pragma unroll
  for (int r = 0; r < 4; ++r) {
    float m = mrun[r], l = lrun[r];
#pragma unroll
    for (int off = 1; off < 16; off <<= 1) {
      float mo = __shfl_xor(m, off);
      float lo = __shfl_xor(l, off);
      float mn = fmaxf(m, mo);
      l = l * __expf(m - mn) + lo * __expf(mo - mn);
      m = mn;
    }
    mrun[r] = m;
    linv[r] = 1.0f / l;
  }

  // ---- pass 2: recompute S, P->LDS bf16, coalesced fp32 P store, PV ----
  f32x4 oacc[8];
#pragma unroll
  for (int jt = 0; jt < 8; ++jt) oacc[jt] = (f32x4){0.f, 0.f, 0.f, 0.f};
  bf16* myPs = Ps[wave];

  for (int t = 0; t < 16; ++t) {
    const int n0 = t * 128;
    if (t < ntc) {
      __syncthreads();
#pragma unroll
      for (int i = 0; i < 8; ++i) {
        int c = i * 256 + tid;
        int row = c & 127, k8 = c >> 7;
        async16(Kh + (size_t)(n0 + row) * D_DIM + k8 * 8, (void*)(KVs + (i * 256 + wave * 64) * 8));
      }
      __builtin_amdgcn_s_waitcnt(0);
      __syncthreads();
      f32x4 sacc[8];
#pragma unroll
      for (int jt = 0; jt < 8; ++jt) sacc[jt] = (f32x4){0.f, 0.f, 0.f, 0.f};
#pragma unroll
      for (int jt = 0; jt < 8; ++jt)
#pragma unroll
        for (int kt = 0; kt < 4; ++kt) {
          bf16x8 bk = *(const bf16x8*)(KVs + ((kt * 4 + quad) * 128 + jt * 16 + l16) * 8);
          sacc[jt] = __builtin_amdgcn_mfma_f32_16x16x32_bf16(aq[kt], bk, sacc[jt], 0, 0, 0);
        }
      const bool full = (n0 + 127 <= m0);
#pragma unroll
      for (int jt = 0; jt < 8; ++jt)
#pragma unroll
        for (int r = 0; r < 4; ++r) {
          float e = __expf(sacc[jt][r] * scale - mrun[r]) * linv[r];
          if (!full) {
            int colg = n0 + jt * 16 + l16;
            e = (colg <= row_base + r) ? e : 0.f;
          }
          int kk = jt * 16 + l16, m = quad * 4 + r;
          myPs[((kk >> 3) * 16 + m) * 8 + (kk & 7)] = (bf16)e;
        }
      asm volatile("s_waitcnt lgkmcnt(0)" ::: "memory");  // wave-local LDS visibility
      bf16x8 ap[4];
#pragma unroll
      for (int kt = 0; kt < 4; ++kt)
        ap[kt] = *(const bf16x8*)(myPs + ((kt * 4 + quad) * 16 + l16) * 8);
      // coalesced fp32 P store (full cache lines)
#pragma unroll
      for (int i = 0; i < 8; ++i) {
        int idx = i * 64 + lane;
        int row = idx >> 5, c0 = (idx & 31) * 4;
        bf16x4 pv = *(const bf16x4*)(myPs + ((c0 >> 3) * 16 + row) * 8 + (c0 & 7));
        float4 o = make_float4((float)pv[0], (float)pv[1], (float)pv[2], (float)pv[3]);
        *(float4*)(Pb + (size_t)(wave * 16 + row) * S_LEN + n0 + c0) = o;
      }
      __syncthreads();  // all waves done with K tile
#pragma unroll
      for (int i = 0; i < 8; ++i) {
        int c = i * 256 + tid;
        int row = c & 127, k8 = c >> 7;  // row = d, k8 = s-chunk
        async16(Vth + (size_t)row * S_LEN + n0 + k8 * 8, (void*)(KVs + (i * 256 + wave * 64) * 8));
      }
      __builtin_amdgcn_s_waitcnt(0);
      __syncthreads();
#pragma unroll
      for (int jt = 0; jt < 8; ++jt)
#pragma unroll
        for (int kt = 0; kt < 4; ++kt) {
          bf16x8 bv = *(const bf16x8*)(KVs + ((kt * 4 + quad) * 128 + jt * 16 + l16) * 8);
          oacc[jt] = __builtin_amdgcn_mfma_f32_16x16x32_bf16(ap[kt], bv, oacc[jt], 0, 0, 0);
        }
    } else {
      float4 z = make_float4(0.f, 0.f, 0.f, 0.f);
#pragma unroll
      for (int i = 0; i < 8; ++i) {
        int idx = i * 256 + tid;
        int row = idx >> 5, c4 = idx & 31;
        *(float4*)(Pb + (size_t)row * S_LEN + n0 + c4 * 4) = z;
      }
    }
  }
  bf16* AOb = AO + ((size_t)(b * S_LEN + m0 + wave * 16 + quad * 4)) * D_DIM + h * DHEAD;
#pragma unroll
  for (int jt = 0; jt < 8; ++jt)
#pragma unroll
    for (int r = 0; r < 4; ++r)
      AOb[(size_t)r * D_DIM + jt * 16 + l16] = (bf16)oacc[jt][r];
}

// ---------------- launcher ----------------
extern "C" void kernel_launch(void* const* d_in, const int* in_sizes, int n_in,
                              void* d_out, int out_size, void* d_ws, size_t ws_size,
                              hipStream_t stream) {
  const float* x  = (const float*)d_in[0];
  const float* wq = (const float*)d_in[2];
  const float* wk = (const float*)d_in[3];
  const float* wv = (const float*)d_in[4];
  const float* wo = (const float*)d_in[5];
  float* out = (float*)d_out;

  bf16* ws = (bf16*)d_ws;
  bf16* Xb = ws;
  bf16* Wq = Xb + NXE;   // Wq|Wk|Wv contiguous = fused weight [6144 x 2048]
  bf16* Wk = Wq + NWE;
  bf16* Wv = Wk + NWE;
  bf16* Wo = Wv + NWE;
  bf16* Qm = Wo + NWE;   // Qm|Km|Vm contiguous
  bf16* Km = Qm + NXE;
  bf16* Vm = Km + NXE;
  bf16* Vt = Vm + NXE;
  bf16* AOm = Vt + NXE;

  cast_kernel<<<(int)(NXE / 4 / 256), 256, 0, stream>>>((const float4*)x, (bf16x4*)Xb, (int)(NXE / 4));
  cast_kernel<<<(int)(NWE / 4 / 256), 256, 0, stream>>>((const float4*)wq, (bf16x4*)Wq, (int)(NWE / 4));
  cast_kernel<<<(int)(NWE / 4 / 256), 256, 0, stream>>>((const float4*)wk, (bf16x4*)Wk, (int)(NWE / 4));
  cast_kernel<<<(int)(NWE / 4 / 256), 256, 0, stream>>>((const float4*)wv, (bf16x4*)Wv, (int)(NWE / 4));
  cast_kernel<<<(int)(NWE / 4 / 256), 256, 0, stream>>>((const float4*)wo, (bf16x4*)Wo, (int)(NWE / 4));

  // fused Q/K/V projection: [4096 x 6144]
  gemm_qkv<<<dim3(3 * D_DIM / 128, BATCH * S_LEN / 128), 256, 0, stream>>>(Xb, Wq, Qm);

  transpose_v<<<dim3(S_LEN / 64, DHEAD / 64, BATCH * NH), 256, 0, stream>>>(Vm, Vt);

  attn_kernel<<<dim3(S_LEN / 64, BATCH * NH), 256, 0, stream>>>(Qm, Km, Vt, out + NXE, AOm);

  gemm_out<<<dim3(D_DIM / 128, BATCH * S_LEN / 128), 256, 0, stream>>>(AOm, Wo, out);
}